// Round 19
// baseline (78.816 us; speedup 1.0000x reference)
//
#include <hip/hip_runtime.h>

#define NTOK 8192
#define NH 16
#define DD 64
#define NEGF -1e30f
#define LOG2E 1.4426950408889634f
#define CUT1 1024

typedef __attribute__((ext_vector_type(8))) short bf16x8;
typedef __attribute__((ext_vector_type(4))) float f32x4;

#define MFMA(a, b, c) __builtin_amdgcn_mfma_f32_16x16x32_bf16((a), (b), (c), 0, 0, 0)
#define EXP2(x) __builtin_amdgcn_exp2f(x)

static __device__ __forceinline__ unsigned short f2bf(float x) {
    union { float f; unsigned u; } c; c.f = x;
    unsigned r = (c.u + 0x7FFFu + ((c.u >> 16) & 1u)) >> 16;
    return (unsigned short)r;
}
static __device__ __forceinline__ float bf2f(unsigned short x) {
    union { unsigned u; float f; } c; c.u = ((unsigned)x) << 16;
    return c.f;
}

// ---------------- fused prep: k->BLOCKED bf16 + v->blocked vt + level-1 pool (k1, vt1) ----------------
// Kb blocked layout: [h][block=32keys][quarter(4) x 512 shorts]; quarter q holds, at slot
// lane*8, the 8 bf16 for lane(g=lane>>4, c=lane&15): key 8*(c>>2)+(c&3)+4*(q>>1), d (q&1)*32+g*8.
__global__ __launch_bounds__(256) void prep_kv1(const float* __restrict__ k, const float* __restrict__ v,
                                                unsigned short* __restrict__ Kb,
                                                unsigned short* __restrict__ vt,
                                                unsigned short* __restrict__ k1,
                                                unsigned short* __restrict__ vt1) {
    int h = blockIdx.x >> 7;
    int n0 = (blockIdx.x & 127) << 6;    // 64 tokens = 2 K-blocks = 8 L1 chunks
    int tid = threadIdx.x;
    __shared__ unsigned short t[64][65];

    // ---- Phase A: V -> LDS (transposed) ----
    {
        int col = tid & 63;      // d
        int rr = tid >> 6;       // 0..3
        const float* src = v + ((size_t)(h * NTOK + n0)) * DD;
#pragma unroll
        for (int r = 0; r < 16; ++r) {
            int row = rr + r * 4;
            t[col][row] = f2bf(src[(size_t)row * DD + col]);
        }
    }
    __syncthreads();
    // vt blocked write
    {
        int d = tid >> 2, ch = tid & 3;
        union { unsigned short u[16]; uint4 q[2]; } tmp;
#pragma unroll
        for (int j = 0; j < 16; ++j) tmp.u[j] = t[d][ch * 16 + j];
        int b = (n0 >> 5) + (ch >> 1);
        unsigned short* dst = vt + ((size_t)(h * 256 + b)) * 2048 + d * 32 + (ch & 1) * 16;
        ((uint4*)dst)[0] = tmp.q[0];
        ((uint4*)dst)[1] = tmp.q[1];
    }
    // vt1 chunk means
    {
        int dd = tid & 63;
        int cc = tid >> 6;
#pragma unroll
        for (int u = 0; u < 2; ++u) {
            int c8 = cc + u * 4;
            float s = 0.f;
#pragma unroll
            for (int r = 0; r < 8; ++r) s += bf2f(t[dd][8 * c8 + r]);
            int C = (n0 >> 3) + c8;
            vt1[((size_t)((h * 32 + (C >> 5)) * DD + dd)) * 32 + (C & 31)] = f2bf(s * 0.125f);
        }
    }
    __syncthreads();

    // ---- Phase B: K convert -> blocked Kb + LDS ----
    {
        int row = tid >> 2, cs = (tid & 3) * 16;
        const float* src = k + ((size_t)(h * NTOK + n0 + row)) * DD + cs;
        float4 f0 = ((const float4*)src)[0], f1 = ((const float4*)src)[1];
        float4 f2 = ((const float4*)src)[2], f3 = ((const float4*)src)[3];
        union { unsigned short u[16]; uint4 q4[2]; } o;
        o.u[0] = f2bf(f0.x); o.u[1] = f2bf(f0.y); o.u[2] = f2bf(f0.z); o.u[3] = f2bf(f0.w);
        o.u[4] = f2bf(f1.x); o.u[5] = f2bf(f1.y); o.u[6] = f2bf(f1.z); o.u[7] = f2bf(f1.w);
        o.u[8] = f2bf(f2.x); o.u[9] = f2bf(f2.y); o.u[10] = f2bf(f2.z); o.u[11] = f2bf(f2.w);
        o.u[12] = f2bf(f3.x); o.u[13] = f2bf(f3.y); o.u[14] = f2bf(f3.z); o.u[15] = f2bf(f3.w);
        // blocked store: 2 x 16B at computed slots
        int grpb = (n0 >> 5) + (row >> 5);
        int kk = row & 31;
        int cw = ((kk >> 3) << 2) | (kk & 3);
        int qd = ((kk >> 2) & 1) * 2 + (cs >= 32 ? 1 : 0);
        int g0w = (cs & 31) >> 3;
        unsigned short* blk = Kb + ((size_t)(h * 256 + grpb)) * 2048 + qd * 512;
        *(uint4*)(blk + (g0w * 16 + cw) * 8) = o.q4[0];
        *(uint4*)(blk + ((g0w + 1) * 16 + cw) * 8) = o.q4[1];
#pragma unroll
        for (int j = 0; j < 16; ++j) t[cs + j][row] = o.u[j];
    }
    __syncthreads();
    // k1 chunk means (row-major, from LDS)
    {
        int dd = tid & 63;
        int cc = tid >> 6;
#pragma unroll
        for (int u = 0; u < 2; ++u) {
            int c8 = cc + u * 4;
            float s = 0.f;
#pragma unroll
            for (int r = 0; r < 8; ++r) s += bf2f(t[dd][8 * c8 + r]);
            int C = (n0 >> 3) + c8;
            k1[((size_t)(h * 1024 + C)) * DD + dd] = f2bf(s * 0.125f);
        }
    }
}

// ---------------- fused level-2 + level-3 pools (one block per head) ----------------
__global__ __launch_bounds__(256) void pool23(const unsigned short* __restrict__ k1,
                                              const unsigned short* __restrict__ vt1,
                                              unsigned short* __restrict__ k2,
                                              unsigned short* __restrict__ vt2,
                                              unsigned short* __restrict__ k3,
                                              unsigned short* __restrict__ vt3) {
    int h = blockIdx.x;
    int tid = threadIdx.x;
    __shared__ unsigned short sk2[128][64];
    __shared__ unsigned short sv2[128][64];

    // phase 1: level-2 means (128 chunks x 64 d; 32 per thread)
#pragma unroll
    for (int i = 0; i < 32; ++i) {
        int idx = tid + i * 256;
        int d = idx & 63;
        int c = idx >> 6;           // 0..127
        const unsigned short* kp = k1 + ((size_t)(h * 1024 + c * 8)) * DD + d;
        float ks = 0.f;
#pragma unroll
        for (int r = 0; r < 8; ++r) ks += bf2f(kp[(size_t)r * DD]);
        const unsigned short* vp = vt1 + ((size_t)((h * 32 + (c >> 2)) * DD + d)) * 32 + 8 * (c & 3);
        union { unsigned short u[8]; uint4 q; } vv;
        vv.q = *(const uint4*)(const void*)vp;
        float vs = 0.f;
#pragma unroll
        for (int j = 0; j < 8; ++j) vs += bf2f(vv.u[j]);
        unsigned short kb = f2bf(ks * 0.125f), vb = f2bf(vs * 0.125f);
        k2[((size_t)(h * 128 + c)) * DD + d] = kb;
        vt2[((size_t)((h * 4 + (c >> 5)) * DD + d)) * 32 + (c & 31)] = vb;
        sk2[c][d] = kb;
        sv2[c][d] = vb;
    }
    __syncthreads();
    // phase 2: level-3 means (32 chunks x 64 d incl. zero pad; 8 per thread)
#pragma unroll
    for (int i = 0; i < 8; ++i) {
        int idx = tid + i * 256;
        int d = idx & 63;
        int c = idx >> 6;           // 0..31
        float ks = 0.f, vs = 0.f;
        if (c < 16) {
#pragma unroll
            for (int j = 0; j < 8; ++j) {
                ks += bf2f(sk2[c * 8 + j][d]);
                vs += bf2f(sv2[c * 8 + j][d]);
            }
            ks *= 0.125f; vs *= 0.125f;
        }
        k3[((size_t)(h * 32 + c)) * DD + d] = f2bf(ks);
        vt3[((size_t)(h * DD + d)) * 32 + c] = f2bf(vs);
    }
}

// K+V fragments of one 32-key group
struct KV32 { bf16x8 k0, k1, k2, k3, v0, v1, v2, v3; };

// ---------------- one 32-key group x 64 queries (4 tiles) ----------------
template<bool L0T, bool INIT>
__device__ __forceinline__ void grp64(
    int c0, int Qs, int lgS, float gp, float gps, float& m,
    const KV32& t, int g, int c,
    const bf16x8* q0, const bf16x8* q1,
    float* lac, f32x4 (*o)[4])
{
    f32x4 z = {0.f, 0.f, 0.f, 0.f};
    f32x4 sA[4], sB[4];
    __builtin_amdgcn_s_setprio(1);
#pragma unroll
    for (int tq = 0; tq < 4; ++tq) {
        sA[tq] = MFMA(t.k1, q1[tq], MFMA(t.k0, q0[tq], z));
        sB[tq] = MFMA(t.k3, q1[tq], MFMA(t.k2, q0[tq], z));
    }
    __builtin_amdgcn_s_setprio(0);

    float sv[4][8];
#pragma unroll
    for (int tq = 0; tq < 4; ++tq) {
        const int QsT = Qs + 16 * tq;
        const int i_q = QsT + c;
        const float negfb = gps * (float)(8 * g) + gp * (float)((1 << lgS) - 1) - gp * (float)i_q;
        bool fastT;
        if (L0T) {
            fastT = (c0 >= QsT - 112) && (c0 + 31 <= QsT);
        } else {
            int num = QsT - 128 - ((1 << lgS) - 1);
            fastT = (num >= 0) && (c0 + 31 <= (num >> lgS));
        }
        if (fastT) {
            float u0 = fmaf(gps, (float)c0, negfb);
            sv[tq][0] = sA[tq][0] + u0;
            sv[tq][1] = sA[tq][1] + fmaf(gps, 1.f, u0);
            sv[tq][2] = sA[tq][2] + fmaf(gps, 2.f, u0);
            sv[tq][3] = sA[tq][3] + fmaf(gps, 3.f, u0);
            sv[tq][4] = sB[tq][0] + fmaf(gps, 4.f, u0);
            sv[tq][5] = sB[tq][1] + fmaf(gps, 5.f, u0);
            sv[tq][6] = sB[tq][2] + fmaf(gps, 6.f, u0);
            sv[tq][7] = sB[tq][3] + fmaf(gps, 7.f, u0);
        } else {
#pragma unroll
            for (int r = 0; r < 4; ++r) {
                int cA = c0 + 8 * g + r, cB = cA + 4;
                int jA = L0T ? cA : (((cA + 1) << lgS) - 1);
                int jB = L0T ? cB : (((cB + 1) << lgS) - 1);
                int dA = i_q - jA, dB = i_q - jB;
                bool aA = L0T ? ((unsigned)dA <= 127u) : (dA >= 128);
                bool aB = L0T ? ((unsigned)dB <= 127u) : (dB >= 128);
                sv[tq][r]     = aA ? fmaf(-gp, (float)dA, sA[tq][r]) : NEGF;
                sv[tq][r + 4] = aB ? fmaf(-gp, (float)dB, sB[tq][r]) : NEGF;
            }
        }
    }

    if (INIT) {
        float tm = NEGF;
#pragma unroll
        for (int tq = 0; tq < 4; ++tq)
#pragma unroll
            for (int r = 0; r < 8; ++r) tm = fmaxf(tm, sv[tq][r]);
        tm = fmaxf(tm, __shfl_xor(tm, 1));
        tm = fmaxf(tm, __shfl_xor(tm, 2));
        tm = fmaxf(tm, __shfl_xor(tm, 4));
        tm = fmaxf(tm, __shfl_xor(tm, 8));
        tm = fmaxf(tm, __shfl_xor(tm, 16));
        tm = fmaxf(tm, __shfl_xor(tm, 32));
        m = tm;
    }

#pragma unroll
    for (int tq = 0; tq < 4; ++tq) {
        float p[8];
#pragma unroll
        for (int r = 0; r < 8; ++r) p[r] = EXP2(sv[tq][r] - m);
        lac[tq] += ((p[0] + p[1]) + (p[2] + p[3])) + ((p[4] + p[5]) + (p[6] + p[7]));
        union { unsigned u32[4]; bf16x8 v8; } pf;
#pragma unroll
        for (int j = 0; j < 4; ++j)
            asm("v_cvt_pk_bf16_f32 %0, %1, %2" : "=v"(pf.u32[j]) : "v"(p[2 * j]), "v"(p[2 * j + 1]));
        __builtin_amdgcn_s_setprio(1);
        o[tq][0] = MFMA(t.v0, pf.v8, o[tq][0]);
        o[tq][1] = MFMA(t.v1, pf.v8, o[tq][1]);
        o[tq][2] = MFMA(t.v2, pf.v8, o[tq][2]);
        o[tq][3] = MFMA(t.v3, pf.v8, o[tq][3]);
        __builtin_amdgcn_s_setprio(0);
    }
}

// ---------------- main attention: 1 wave/block, 64 queries/wave, LPT, HW refill ----------------
__global__ __launch_bounds__(64, 1) void attn_mfma(
    const float* __restrict__ q, const unsigned short* __restrict__ Kb,
    const unsigned short* __restrict__ Vtb,
    const unsigned short* __restrict__ K1, const unsigned short* __restrict__ Vt1,
    const unsigned short* __restrict__ K2, const unsigned short* __restrict__ Vt2,
    const unsigned short* __restrict__ K3, const unsigned short* __restrict__ Vt3,
    const float* __restrict__ gam, float* __restrict__ out) {
    const int lane = threadIdx.x;
    const int h = blockIdx.x & 15;            // head->XCD pinning for L2 locality
    const int qpos = 127 - (blockIdx.x >> 4); // LPT: heaviest (late) positions dispatch first
    const int Qs = qpos << 6;                 // 64 queries per wave
    const int g = lane >> 4;
    const int c = lane & 15;

    const float g0 = gam[0] * LOG2E, g1 = gam[1] * LOG2E;
    const float g2 = gam[2] * LOG2E, g3 = gam[3] * LOG2E;

    // L0: blocked K + blocked V (both read-order; 8 contiguous 1KB loads per group)
    const unsigned short* KbB = Kb + (size_t)h * 256 * 2048 + lane * 8;
    const unsigned short* VtH = Vtb + (size_t)h * 256 * 2048 + c * 32 + g * 8;
    // pooled levels: row-major K (key-permuted) + blocked V
    const size_t kperm = ((size_t)(8 * (c >> 2) + (c & 3))) * DD + g * 8;
    const unsigned short* K1H = K1 + (size_t)h * 1024 * DD + kperm;
    const unsigned short* V1H = Vt1 + (size_t)h * 32 * 2048 + c * 32 + g * 8;
    const unsigned short* K2H = K2 + (size_t)h * 128 * DD + kperm;
    const unsigned short* V2H = Vt2 + (size_t)h * 4 * 2048 + c * 32 + g * 8;
    const unsigned short* K3H = K3 + (size_t)h * 32 * DD + kperm;
    const unsigned short* V3H = Vt3 + (size_t)h * 2048 + c * 32 + g * 8;

    auto LOADKV0 = [&](int c0) -> KV32 {   // L0: fully blocked
        KV32 r;
        const unsigned short* ka = KbB + (size_t)(c0 >> 5) * 2048;
        r.k0 = *(const bf16x8*)(const void*)(ka);
        r.k1 = *(const bf16x8*)(const void*)(ka + 512);
        r.k2 = *(const bf16x8*)(const void*)(ka + 1024);
        r.k3 = *(const bf16x8*)(const void*)(ka + 1536);
        const unsigned short* va = VtH + (size_t)(c0 >> 5) * 2048;
        r.v0 = *(const bf16x8*)(const void*)(va);
        r.v1 = *(const bf16x8*)(const void*)(va + 512);
        r.v2 = *(const bf16x8*)(const void*)(va + 1024);
        r.v3 = *(const bf16x8*)(const void*)(va + 1536);
        return r;
    };
    auto LOADKV = [&](const unsigned short* Kh, const unsigned short* Vh, int c0) -> KV32 {
        KV32 r;
        const unsigned short* ka = Kh + (size_t)c0 * DD;
        r.k0 = *(const bf16x8*)(const void*)(ka);
        r.k1 = *(const bf16x8*)(const void*)(ka + 32);
        r.k2 = *(const bf16x8*)(const void*)(ka + 4 * DD);
        r.k3 = *(const bf16x8*)(const void*)(ka + 4 * DD + 32);
        const unsigned short* va = Vh + (size_t)(c0 >> 5) * 2048;
        r.v0 = *(const bf16x8*)(const void*)(va);
        r.v1 = *(const bf16x8*)(const void*)(va + 512);
        r.v2 = *(const bf16x8*)(const void*)(va + 1024);
        r.v3 = *(const bf16x8*)(const void*)(va + 1536);
        return r;
    };

    // Q fragments: 4 tiles, fp32 load + scale + pack
    const float qsc = 0.125f * LOG2E;
    bf16x8 q0[4], q1[4];
#pragma unroll
    for (int tq = 0; tq < 4; ++tq) {
        const float* qr = q + ((size_t)(h * NTOK + Qs + 16 * tq + c)) * DD;
        float4 x0 = *(const float4*)(qr + g * 8),      x1 = *(const float4*)(qr + g * 8 + 4);
        float4 x2 = *(const float4*)(qr + 32 + g * 8), x3 = *(const float4*)(qr + 32 + g * 8 + 4);
        union { unsigned u32[4]; bf16x8 v8; } pA, pB;
        asm("v_cvt_pk_bf16_f32 %0, %1, %2" : "=v"(pA.u32[0]) : "v"(x0.x * qsc), "v"(x0.y * qsc));
        asm("v_cvt_pk_bf16_f32 %0, %1, %2" : "=v"(pA.u32[1]) : "v"(x0.z * qsc), "v"(x0.w * qsc));
        asm("v_cvt_pk_bf16_f32 %0, %1, %2" : "=v"(pA.u32[2]) : "v"(x1.x * qsc), "v"(x1.y * qsc));
        asm("v_cvt_pk_bf16_f32 %0, %1, %2" : "=v"(pA.u32[3]) : "v"(x1.z * qsc), "v"(x1.w * qsc));
        asm("v_cvt_pk_bf16_f32 %0, %1, %2" : "=v"(pB.u32[0]) : "v"(x2.x * qsc), "v"(x2.y * qsc));
        asm("v_cvt_pk_bf16_f32 %0, %1, %2" : "=v"(pB.u32[1]) : "v"(x2.z * qsc), "v"(x2.w * qsc));
        asm("v_cvt_pk_bf16_f32 %0, %1, %2" : "=v"(pB.u32[2]) : "v"(x3.x * qsc), "v"(x3.y * qsc));
        asm("v_cvt_pk_bf16_f32 %0, %1, %2" : "=v"(pB.u32[3]) : "v"(x3.z * qsc), "v"(x3.w * qsc));
        q0[tq] = pA.v8; q1[tq] = pB.v8;
    }

    f32x4 o[4][4];
#pragma unroll
    for (int tq = 0; tq < 4; ++tq)
#pragma unroll
        for (int db = 0; db < 4; ++db) o[tq][db] = (f32x4){0.f, 0.f, 0.f, 0.f};
    float lac[4] = {0.f, 0.f, 0.f, 0.f};
    float m = NEGF;

    // ---- L0 newest group (keys Qs+32..Qs+63): INIT m ----
    {
        KV32 t = LOADKV0(Qs + 32);
        grp64<true, true>(Qs + 32, Qs, 0, g0, g0, m, t, g, c, q0, q1, lac, o);
    }
    // ---- L0 remaining groups, paired ----
    {
        int lo0 = Qs - 127; if (lo0 < 0) lo0 = 0; lo0 &= ~31;
        int c0 = Qs;
        while (c0 - 32 >= lo0) {
            KV32 a = LOADKV0(c0);
            KV32 b = LOADKV0(c0 - 32);
            grp64<true, false>(c0,      Qs, 0, g0, g0, m, a, g, c, q0, q1, lac, o);
            grp64<true, false>(c0 - 32, Qs, 0, g0, g0, m, b, g, c, q0, q1, lac, o);
            c0 -= 64;
        }
        if (c0 >= lo0) {
            KV32 a = LOADKV0(c0);
            grp64<true, false>(c0, Qs, 0, g0, g0, m, a, g, c, q0, q1, lac, o);
        }
    }
    // ---- L1, truncated at CUT1 tokens, paired ----
    {
        int cm = Qs - 72;                   // (Qs+63)-128-7
        if (cm >= 0) {
            int top = (cm >> 3) & ~31;
            int lo = Qs - CUT1;
            lo = (lo <= 0) ? 0 : ((lo >> 3) & ~31);
            int c0 = top;
            while (c0 - 32 >= lo) {
                KV32 a = LOADKV(K1H, V1H, c0);
                KV32 b = LOADKV(K1H, V1H, c0 - 32);
                grp64<false, false>(c0,      Qs, 3, g1, g1 * 8.f, m, a, g, c, q0, q1, lac, o);
                grp64<false, false>(c0 - 32, Qs, 3, g1, g1 * 8.f, m, b, g, c, q0, q1, lac, o);
                c0 -= 64;
            }
            if (c0 >= lo) {
                KV32 a = LOADKV(K1H, V1H, c0);
                grp64<false, false>(c0, Qs, 3, g1, g1 * 8.f, m, a, g, c, q0, q1, lac, o);
            }
        }
    }
    // ---- L2, paired ----
    {
        int cm2 = Qs - 128;                 // (Qs+63)-128-63
        if (cm2 >= 0) {
            int c0 = (cm2 >> 6) & ~31;
            while (c0 - 32 >= 0) {
                KV32 a = LOADKV(K2H, V2H, c0);
                KV32 b = LOADKV(K2H, V2H, c0 - 32);
                grp64<false, false>(c0,      Qs, 6, g2, g2 * 64.f, m, a, g, c, q0, q1, lac, o);
                grp64<false, false>(c0 - 32, Qs, 6, g2, g2 * 64.f, m, b, g, c, q0, q1, lac, o);
                c0 -= 64;
            }
            if (c0 >= 0) {
                KV32 a = LOADKV(K2H, V2H, c0);
                grp64<false, false>(c0, Qs, 6, g2, g2 * 64.f, m, a, g, c, q0, q1, lac, o);
            }
        }
    }
    // ---- L3 single group ----
    {
        if (Qs >= 576) {                    // (Qs+63)-128-511 >= 0
            KV32 t = LOADKV(K3H, V3H, 0);
            grp64<false, false>(0, Qs, 9, g3, g3 * 512.f, m, t, g, c, q0, q1, lac, o);
        }
    }

    // ---- per-tile l reduce + write ----
#pragma unroll
    for (int tq = 0; tq < 4; ++tq) {
        float lt = lac[tq] + __shfl_xor(lac[tq], 16);
        lt += __shfl_xor(lt, 32);
        float inv = 1.0f / fmaxf(lt, 1e-8f);
        float* orow = out + ((size_t)(h * NTOK + Qs + 16 * tq + c)) * DD;
#pragma unroll
        for (int db = 0; db < 4; ++db) {
            float4 x;
            x.x = o[tq][db][0] * inv; x.y = o[tq][db][1] * inv;
            x.z = o[tq][db][2] * inv; x.w = o[tq][db][3] * inv;
            *(float4*)(orow + db * 16 + 4 * g) = x;
        }
    }
}

extern "C" void kernel_launch(void* const* d_in, const int* in_sizes, int n_in,
                              void* d_out, int out_size, void* d_ws, size_t ws_size,
                              hipStream_t stream) {
    const float* q = (const float*)d_in[0];
    const float* k = (const float*)d_in[1];
    const float* v = (const float*)d_in[2];
    const float* gam = (const float*)d_in[3];
    float* out = (float*)d_out;

    char* w = (char*)d_ws;
    const size_t bigN = (size_t)NH * NTOK * DD * sizeof(unsigned short);
    unsigned short* Kbuf = (unsigned short*)w;  w += bigN;
    unsigned short* Vtb  = (unsigned short*)w;  w += bigN;
    unsigned short* K1   = (unsigned short*)w;  w += (size_t)NH * 1024 * DD * 2;
    unsigned short* Vt1  = (unsigned short*)w;  w += (size_t)NH * 1024 * DD * 2;
    unsigned short* K2   = (unsigned short*)w;  w += (size_t)NH * 128 * DD * 2;
    unsigned short* Vt2  = (unsigned short*)w;  w += (size_t)NH * 128 * DD * 2;
    unsigned short* K3   = (unsigned short*)w;  w += (size_t)NH * 32 * DD * 2;
    unsigned short* Vt3  = (unsigned short*)w;  w += (size_t)NH * 32 * DD * 2;

    prep_kv1<<<NH * (NTOK / 64), 256, 0, stream>>>(k, v, Kbuf, Vtb, K1, Vt1);
    pool23<<<NH, 256, 0, stream>>>(K1, Vt1, K2, Vt2, K3, Vt3);

    attn_mfma<<<NH * 128, 64, 0, stream>>>(q, Kbuf, Vtb, K1, Vt1, K2, Vt2, K3, Vt3, gam, out);
}

// Round 20
// 71.353 us; speedup vs baseline: 1.1046x; 1.1046x over previous
//
#include <hip/hip_runtime.h>

#define NTOK 8192
#define NH 16
#define DD 64
#define NEGF -1e30f
#define LOG2E 1.4426950408889634f
#define CUT1 1024

typedef __attribute__((ext_vector_type(8))) short bf16x8;
typedef __attribute__((ext_vector_type(4))) float f32x4;

#define MFMA(a, b, c) __builtin_amdgcn_mfma_f32_16x16x32_bf16((a), (b), (c), 0, 0, 0)
#define EXP2(x) __builtin_amdgcn_exp2f(x)

static __device__ __forceinline__ unsigned short f2bf(float x) {
    union { float f; unsigned u; } c; c.f = x;
    unsigned r = (c.u + 0x7FFFu + ((c.u >> 16) & 1u)) >> 16;
    return (unsigned short)r;
}
static __device__ __forceinline__ float bf2f(unsigned short x) {
    union { unsigned u; float f; } c; c.u = ((unsigned)x) << 16;
    return c.f;
}

// ---------------- fused prep: k->BLOCKED bf16 + v->blocked vt + level-1 pool (k1, vt1) ----------------
// Kb blocked layout: [h][block=32keys][quarter(4) x 512 shorts]; quarter q holds, at slot
// lane*8, the 8 bf16 for lane(g=lane>>4, c=lane&15): key 8*(c>>2)+(c&3)+4*(q>>1), d (q&1)*32+g*8.
__global__ __launch_bounds__(256) void prep_kv1(const float* __restrict__ k, const float* __restrict__ v,
                                                unsigned short* __restrict__ Kb,
                                                unsigned short* __restrict__ vt,
                                                unsigned short* __restrict__ k1,
                                                unsigned short* __restrict__ vt1) {
    int h = blockIdx.x >> 7;
    int n0 = (blockIdx.x & 127) << 6;    // 64 tokens = 2 K-blocks = 8 L1 chunks
    int tid = threadIdx.x;
    __shared__ unsigned short t[64][65];

    // ---- Phase A: V -> LDS (transposed) ----
    {
        int col = tid & 63;      // d
        int rr = tid >> 6;       // 0..3
        const float* src = v + ((size_t)(h * NTOK + n0)) * DD;
#pragma unroll
        for (int r = 0; r < 16; ++r) {
            int row = rr + r * 4;
            t[col][row] = f2bf(src[(size_t)row * DD + col]);
        }
    }
    __syncthreads();
    // vt blocked write
    {
        int d = tid >> 2, ch = tid & 3;
        union { unsigned short u[16]; uint4 q[2]; } tmp;
#pragma unroll
        for (int j = 0; j < 16; ++j) tmp.u[j] = t[d][ch * 16 + j];
        int b = (n0 >> 5) + (ch >> 1);
        unsigned short* dst = vt + ((size_t)(h * 256 + b)) * 2048 + d * 32 + (ch & 1) * 16;
        ((uint4*)dst)[0] = tmp.q[0];
        ((uint4*)dst)[1] = tmp.q[1];
    }
    // vt1 chunk means
    {
        int dd = tid & 63;
        int cc = tid >> 6;
#pragma unroll
        for (int u = 0; u < 2; ++u) {
            int c8 = cc + u * 4;
            float s = 0.f;
#pragma unroll
            for (int r = 0; r < 8; ++r) s += bf2f(t[dd][8 * c8 + r]);
            int C = (n0 >> 3) + c8;
            vt1[((size_t)((h * 32 + (C >> 5)) * DD + dd)) * 32 + (C & 31)] = f2bf(s * 0.125f);
        }
    }
    __syncthreads();

    // ---- Phase B: K convert -> blocked Kb + LDS ----
    {
        int row = tid >> 2, cs = (tid & 3) * 16;
        const float* src = k + ((size_t)(h * NTOK + n0 + row)) * DD + cs;
        float4 f0 = ((const float4*)src)[0], f1 = ((const float4*)src)[1];
        float4 f2 = ((const float4*)src)[2], f3 = ((const float4*)src)[3];
        union { unsigned short u[16]; uint4 q4[2]; } o;
        o.u[0] = f2bf(f0.x); o.u[1] = f2bf(f0.y); o.u[2] = f2bf(f0.z); o.u[3] = f2bf(f0.w);
        o.u[4] = f2bf(f1.x); o.u[5] = f2bf(f1.y); o.u[6] = f2bf(f1.z); o.u[7] = f2bf(f1.w);
        o.u[8] = f2bf(f2.x); o.u[9] = f2bf(f2.y); o.u[10] = f2bf(f2.z); o.u[11] = f2bf(f2.w);
        o.u[12] = f2bf(f3.x); o.u[13] = f2bf(f3.y); o.u[14] = f2bf(f3.z); o.u[15] = f2bf(f3.w);
        // blocked store: 2 x 16B at computed slots
        int grpb = (n0 >> 5) + (row >> 5);
        int kk = row & 31;
        int cw = ((kk >> 3) << 2) | (kk & 3);
        int qd = ((kk >> 2) & 1) * 2 + (cs >= 32 ? 1 : 0);
        int g0w = (cs & 31) >> 3;
        unsigned short* blk = Kb + ((size_t)(h * 256 + grpb)) * 2048 + qd * 512;
        *(uint4*)(blk + (g0w * 16 + cw) * 8) = o.q4[0];
        *(uint4*)(blk + ((g0w + 1) * 16 + cw) * 8) = o.q4[1];
#pragma unroll
        for (int j = 0; j < 16; ++j) t[cs + j][row] = o.u[j];
    }
    __syncthreads();
    // k1 chunk means (row-major, from LDS)
    {
        int dd = tid & 63;
        int cc = tid >> 6;
#pragma unroll
        for (int u = 0; u < 2; ++u) {
            int c8 = cc + u * 4;
            float s = 0.f;
#pragma unroll
            for (int r = 0; r < 8; ++r) s += bf2f(t[dd][8 * c8 + r]);
            int C = (n0 >> 3) + c8;
            k1[((size_t)(h * 1024 + C)) * DD + dd] = f2bf(s * 0.125f);
        }
    }
}

// ---------------- level-2 pool ----------------
__global__ __launch_bounds__(256) void pool2_b(const unsigned short* __restrict__ k1,
                                               const unsigned short* __restrict__ vt1,
                                               unsigned short* __restrict__ k2,
                                               unsigned short* __restrict__ vt2) {
    int tid = blockIdx.x * blockDim.x + threadIdx.x;
    int d = tid & 63;
    int c = (tid >> 6) & 127;
    int h = tid >> 13;
    const unsigned short* kp = k1 + ((size_t)(h * 1024 + c * 8)) * DD + d;
    float ks = 0.f;
#pragma unroll
    for (int r = 0; r < 8; ++r) ks += bf2f(kp[(size_t)r * DD]);
    const unsigned short* vp = vt1 + ((size_t)((h * 32 + (c >> 2)) * DD + d)) * 32 + 8 * (c & 3);
    union { unsigned short u[8]; uint4 q; } vv;
    vv.q = *(const uint4*)(const void*)vp;
    float vs = 0.f;
#pragma unroll
    for (int j = 0; j < 8; ++j) vs += bf2f(vv.u[j]);
    k2[((size_t)(h * 128 + c)) * DD + d] = f2bf(ks * 0.125f);
    vt2[((size_t)((h * 4 + (c >> 5)) * DD + d)) * 32 + (c & 31)] = f2bf(vs * 0.125f);
}

// ---------------- level-3 pool (16 real chunks, padded to 32) ----------------
__global__ __launch_bounds__(256) void pool3_b(const unsigned short* __restrict__ k2,
                                               const unsigned short* __restrict__ vt2,
                                               unsigned short* __restrict__ k3,
                                               unsigned short* __restrict__ vt3) {
    int tid = blockIdx.x * blockDim.x + threadIdx.x;
    int d = tid & 63;
    int c = (tid >> 6) & 31;
    int h = tid >> 11;
    float ks = 0.f, vs = 0.f;
    if (c < 16) {
        const unsigned short* kp = k2 + ((size_t)(h * 128 + c * 8)) * DD + d;
#pragma unroll
        for (int r = 0; r < 8; ++r) ks += bf2f(kp[(size_t)r * DD]);
        const unsigned short* vp = vt2 + ((size_t)((h * 4 + (c >> 2)) * DD + d)) * 32 + 8 * (c & 3);
        union { unsigned short u[8]; uint4 q; } vv;
        vv.q = *(const uint4*)(const void*)vp;
#pragma unroll
        for (int j = 0; j < 8; ++j) vs += bf2f(vv.u[j]);
        ks *= 0.125f; vs *= 0.125f;
    }
    k3[((size_t)(h * 32 + c)) * DD + d] = f2bf(ks);
    vt3[((size_t)(h * DD + d)) * 32 + c] = f2bf(vs);
}

// K+V fragments of one 32-key group
struct KV32 { bf16x8 k0, k1, k2, k3, v0, v1, v2, v3; };

// ---------------- one 32-key group x 64 queries (4 tiles) ----------------
template<bool L0T, bool INIT>
__device__ __forceinline__ void grp64(
    int c0, int Qs, int lgS, float gp, float gps, float& m,
    const KV32& t, int g, int c,
    const bf16x8* q0, const bf16x8* q1,
    float* lac, f32x4 (*o)[4])
{
    f32x4 z = {0.f, 0.f, 0.f, 0.f};
    f32x4 sA[4], sB[4];
    __builtin_amdgcn_s_setprio(1);
#pragma unroll
    for (int tq = 0; tq < 4; ++tq) {
        sA[tq] = MFMA(t.k1, q1[tq], MFMA(t.k0, q0[tq], z));
        sB[tq] = MFMA(t.k3, q1[tq], MFMA(t.k2, q0[tq], z));
    }
    __builtin_amdgcn_s_setprio(0);

    float sv[4][8];
#pragma unroll
    for (int tq = 0; tq < 4; ++tq) {
        const int QsT = Qs + 16 * tq;
        const int i_q = QsT + c;
        const float negfb = gps * (float)(8 * g) + gp * (float)((1 << lgS) - 1) - gp * (float)i_q;
        bool fastT;
        if (L0T) {
            fastT = (c0 >= QsT - 112) && (c0 + 31 <= QsT);
        } else {
            int num = QsT - 128 - ((1 << lgS) - 1);
            fastT = (num >= 0) && (c0 + 31 <= (num >> lgS));
        }
        if (fastT) {
            float u0 = fmaf(gps, (float)c0, negfb);
            sv[tq][0] = sA[tq][0] + u0;
            sv[tq][1] = sA[tq][1] + fmaf(gps, 1.f, u0);
            sv[tq][2] = sA[tq][2] + fmaf(gps, 2.f, u0);
            sv[tq][3] = sA[tq][3] + fmaf(gps, 3.f, u0);
            sv[tq][4] = sB[tq][0] + fmaf(gps, 4.f, u0);
            sv[tq][5] = sB[tq][1] + fmaf(gps, 5.f, u0);
            sv[tq][6] = sB[tq][2] + fmaf(gps, 6.f, u0);
            sv[tq][7] = sB[tq][3] + fmaf(gps, 7.f, u0);
        } else {
#pragma unroll
            for (int r = 0; r < 4; ++r) {
                int cA = c0 + 8 * g + r, cB = cA + 4;
                int jA = L0T ? cA : (((cA + 1) << lgS) - 1);
                int jB = L0T ? cB : (((cB + 1) << lgS) - 1);
                int dA = i_q - jA, dB = i_q - jB;
                bool aA = L0T ? ((unsigned)dA <= 127u) : (dA >= 128);
                bool aB = L0T ? ((unsigned)dB <= 127u) : (dB >= 128);
                sv[tq][r]     = aA ? fmaf(-gp, (float)dA, sA[tq][r]) : NEGF;
                sv[tq][r + 4] = aB ? fmaf(-gp, (float)dB, sB[tq][r]) : NEGF;
            }
        }
    }

    if (INIT) {
        float tm = NEGF;
#pragma unroll
        for (int tq = 0; tq < 4; ++tq)
#pragma unroll
            for (int r = 0; r < 8; ++r) tm = fmaxf(tm, sv[tq][r]);
        tm = fmaxf(tm, __shfl_xor(tm, 1));
        tm = fmaxf(tm, __shfl_xor(tm, 2));
        tm = fmaxf(tm, __shfl_xor(tm, 4));
        tm = fmaxf(tm, __shfl_xor(tm, 8));
        tm = fmaxf(tm, __shfl_xor(tm, 16));
        tm = fmaxf(tm, __shfl_xor(tm, 32));
        m = tm;
    }

#pragma unroll
    for (int tq = 0; tq < 4; ++tq) {
        float p[8];
#pragma unroll
        for (int r = 0; r < 8; ++r) p[r] = EXP2(sv[tq][r] - m);
        lac[tq] += ((p[0] + p[1]) + (p[2] + p[3])) + ((p[4] + p[5]) + (p[6] + p[7]));
        union { unsigned u32[4]; bf16x8 v8; } pf;
#pragma unroll
        for (int j = 0; j < 4; ++j)
            asm("v_cvt_pk_bf16_f32 %0, %1, %2" : "=v"(pf.u32[j]) : "v"(p[2 * j]), "v"(p[2 * j + 1]));
        __builtin_amdgcn_s_setprio(1);
        o[tq][0] = MFMA(t.v0, pf.v8, o[tq][0]);
        o[tq][1] = MFMA(t.v1, pf.v8, o[tq][1]);
        o[tq][2] = MFMA(t.v2, pf.v8, o[tq][2]);
        o[tq][3] = MFMA(t.v3, pf.v8, o[tq][3]);
        __builtin_amdgcn_s_setprio(0);
    }
}

// ---------------- main attention: 1 wave/block, 64 queries/wave, LPT, HW refill ----------------
__global__ __launch_bounds__(64, 1) void attn_mfma(
    const float* __restrict__ q, const unsigned short* __restrict__ Kb,
    const unsigned short* __restrict__ Vtb,
    const unsigned short* __restrict__ K1, const unsigned short* __restrict__ Vt1,
    const unsigned short* __restrict__ K2, const unsigned short* __restrict__ Vt2,
    const unsigned short* __restrict__ K3, const unsigned short* __restrict__ Vt3,
    const float* __restrict__ gam, float* __restrict__ out) {
    const int lane = threadIdx.x;
    const int h = blockIdx.x & 15;            // head->XCD pinning for L2 locality
    const int qpos = 127 - (blockIdx.x >> 4); // LPT: heaviest (late) positions dispatch first
    const int Qs = qpos << 6;                 // 64 queries per wave
    const int g = lane >> 4;
    const int c = lane & 15;

    const float g0 = gam[0] * LOG2E, g1 = gam[1] * LOG2E;
    const float g2 = gam[2] * LOG2E, g3 = gam[3] * LOG2E;

    // L0: blocked K + blocked V (both read-order; 8 contiguous 1KB loads per group)
    const unsigned short* KbB = Kb + (size_t)h * 256 * 2048 + lane * 8;
    const unsigned short* VtH = Vtb + (size_t)h * 256 * 2048 + c * 32 + g * 8;
    // pooled levels: row-major K (key-permuted) + blocked V
    const size_t kperm = ((size_t)(8 * (c >> 2) + (c & 3))) * DD + g * 8;
    const unsigned short* K1H = K1 + (size_t)h * 1024 * DD + kperm;
    const unsigned short* V1H = Vt1 + (size_t)h * 32 * 2048 + c * 32 + g * 8;
    const unsigned short* K2H = K2 + (size_t)h * 128 * DD + kperm;
    const unsigned short* V2H = Vt2 + (size_t)h * 4 * 2048 + c * 32 + g * 8;
    const unsigned short* K3H = K3 + (size_t)h * 32 * DD + kperm;
    const unsigned short* V3H = Vt3 + (size_t)h * 2048 + c * 32 + g * 8;

    auto LOADKV0 = [&](int c0) -> KV32 {   // L0: fully blocked
        KV32 r;
        const unsigned short* ka = KbB + (size_t)(c0 >> 5) * 2048;
        r.k0 = *(const bf16x8*)(const void*)(ka);
        r.k1 = *(const bf16x8*)(const void*)(ka + 512);
        r.k2 = *(const bf16x8*)(const void*)(ka + 1024);
        r.k3 = *(const bf16x8*)(const void*)(ka + 1536);
        const unsigned short* va = VtH + (size_t)(c0 >> 5) * 2048;
        r.v0 = *(const bf16x8*)(const void*)(va);
        r.v1 = *(const bf16x8*)(const void*)(va + 512);
        r.v2 = *(const bf16x8*)(const void*)(va + 1024);
        r.v3 = *(const bf16x8*)(const void*)(va + 1536);
        return r;
    };
    auto LOADKV = [&](const unsigned short* Kh, const unsigned short* Vh, int c0) -> KV32 {
        KV32 r;
        const unsigned short* ka = Kh + (size_t)c0 * DD;
        r.k0 = *(const bf16x8*)(const void*)(ka);
        r.k1 = *(const bf16x8*)(const void*)(ka + 32);
        r.k2 = *(const bf16x8*)(const void*)(ka + 4 * DD);
        r.k3 = *(const bf16x8*)(const void*)(ka + 4 * DD + 32);
        const unsigned short* va = Vh + (size_t)(c0 >> 5) * 2048;
        r.v0 = *(const bf16x8*)(const void*)(va);
        r.v1 = *(const bf16x8*)(const void*)(va + 512);
        r.v2 = *(const bf16x8*)(const void*)(va + 1024);
        r.v3 = *(const bf16x8*)(const void*)(va + 1536);
        return r;
    };

    // Q fragments: 4 tiles, fp32 load + scale + pack
    const float qsc = 0.125f * LOG2E;
    bf16x8 q0[4], q1[4];
#pragma unroll
    for (int tq = 0; tq < 4; ++tq) {
        const float* qr = q + ((size_t)(h * NTOK + Qs + 16 * tq + c)) * DD;
        float4 x0 = *(const float4*)(qr + g * 8),      x1 = *(const float4*)(qr + g * 8 + 4);
        float4 x2 = *(const float4*)(qr + 32 + g * 8), x3 = *(const float4*)(qr + 32 + g * 8 + 4);
        union { unsigned u32[4]; bf16x8 v8; } pA, pB;
        asm("v_cvt_pk_bf16_f32 %0, %1, %2" : "=v"(pA.u32[0]) : "v"(x0.x * qsc), "v"(x0.y * qsc));
        asm("v_cvt_pk_bf16_f32 %0, %1, %2" : "=v"(pA.u32[1]) : "v"(x0.z * qsc), "v"(x0.w * qsc));
        asm("v_cvt_pk_bf16_f32 %0, %1, %2" : "=v"(pA.u32[2]) : "v"(x1.x * qsc), "v"(x1.y * qsc));
        asm("v_cvt_pk_bf16_f32 %0, %1, %2" : "=v"(pA.u32[3]) : "v"(x1.z * qsc), "v"(x1.w * qsc));
        asm("v_cvt_pk_bf16_f32 %0, %1, %2" : "=v"(pB.u32[0]) : "v"(x2.x * qsc), "v"(x2.y * qsc));
        asm("v_cvt_pk_bf16_f32 %0, %1, %2" : "=v"(pB.u32[1]) : "v"(x2.z * qsc), "v"(x2.w * qsc));
        asm("v_cvt_pk_bf16_f32 %0, %1, %2" : "=v"(pB.u32[2]) : "v"(x3.x * qsc), "v"(x3.y * qsc));
        asm("v_cvt_pk_bf16_f32 %0, %1, %2" : "=v"(pB.u32[3]) : "v"(x3.z * qsc), "v"(x3.w * qsc));
        q0[tq] = pA.v8; q1[tq] = pB.v8;
    }

    f32x4 o[4][4];
#pragma unroll
    for (int tq = 0; tq < 4; ++tq)
#pragma unroll
        for (int db = 0; db < 4; ++db) o[tq][db] = (f32x4){0.f, 0.f, 0.f, 0.f};
    float lac[4] = {0.f, 0.f, 0.f, 0.f};
    float m = NEGF;

    // ---- L0 newest group (keys Qs+32..Qs+63): INIT m ----
    {
        KV32 t = LOADKV0(Qs + 32);
        grp64<true, true>(Qs + 32, Qs, 0, g0, g0, m, t, g, c, q0, q1, lac, o);
    }
    // ---- L0 remaining groups, paired ----
    {
        int lo0 = Qs - 127; if (lo0 < 0) lo0 = 0; lo0 &= ~31;
        int c0 = Qs;
        while (c0 - 32 >= lo0) {
            KV32 a = LOADKV0(c0);
            KV32 b = LOADKV0(c0 - 32);
            grp64<true, false>(c0,      Qs, 0, g0, g0, m, a, g, c, q0, q1, lac, o);
            grp64<true, false>(c0 - 32, Qs, 0, g0, g0, m, b, g, c, q0, q1, lac, o);
            c0 -= 64;
        }
        if (c0 >= lo0) {
            KV32 a = LOADKV0(c0);
            grp64<true, false>(c0, Qs, 0, g0, g0, m, a, g, c, q0, q1, lac, o);
        }
    }
    // ---- L1, truncated at CUT1 tokens, paired ----
    {
        int cm = Qs - 72;                   // (Qs+63)-128-7
        if (cm >= 0) {
            int top = (cm >> 3) & ~31;
            int lo = Qs - CUT1;
            lo = (lo <= 0) ? 0 : ((lo >> 3) & ~31);
            int c0 = top;
            while (c0 - 32 >= lo) {
                KV32 a = LOADKV(K1H, V1H, c0);
                KV32 b = LOADKV(K1H, V1H, c0 - 32);
                grp64<false, false>(c0,      Qs, 3, g1, g1 * 8.f, m, a, g, c, q0, q1, lac, o);
                grp64<false, false>(c0 - 32, Qs, 3, g1, g1 * 8.f, m, b, g, c, q0, q1, lac, o);
                c0 -= 64;
            }
            if (c0 >= lo) {
                KV32 a = LOADKV(K1H, V1H, c0);
                grp64<false, false>(c0, Qs, 3, g1, g1 * 8.f, m, a, g, c, q0, q1, lac, o);
            }
        }
    }
    // ---- L2, paired ----
    {
        int cm2 = Qs - 128;                 // (Qs+63)-128-63
        if (cm2 >= 0) {
            int c0 = (cm2 >> 6) & ~31;
            while (c0 - 32 >= 0) {
                KV32 a = LOADKV(K2H, V2H, c0);
                KV32 b = LOADKV(K2H, V2H, c0 - 32);
                grp64<false, false>(c0,      Qs, 6, g2, g2 * 64.f, m, a, g, c, q0, q1, lac, o);
                grp64<false, false>(c0 - 32, Qs, 6, g2, g2 * 64.f, m, b, g, c, q0, q1, lac, o);
                c0 -= 64;
            }
            if (c0 >= 0) {
                KV32 a = LOADKV(K2H, V2H, c0);
                grp64<false, false>(c0, Qs, 6, g2, g2 * 64.f, m, a, g, c, q0, q1, lac, o);
            }
        }
    }
    // ---- L3 single group ----
    {
        if (Qs >= 576) {                    // (Qs+63)-128-511 >= 0
            KV32 t = LOADKV(K3H, V3H, 0);
            grp64<false, false>(0, Qs, 9, g3, g3 * 512.f, m, t, g, c, q0, q1, lac, o);
        }
    }

    // ---- per-tile l reduce + write ----
#pragma unroll
    for (int tq = 0; tq < 4; ++tq) {
        float lt = lac[tq] + __shfl_xor(lac[tq], 16);
        lt += __shfl_xor(lt, 32);
        float inv = 1.0f / fmaxf(lt, 1e-8f);
        float* orow = out + ((size_t)(h * NTOK + Qs + 16 * tq + c)) * DD;
#pragma unroll
        for (int db = 0; db < 4; ++db) {
            float4 x;
            x.x = o[tq][db][0] * inv; x.y = o[tq][db][1] * inv;
            x.z = o[tq][db][2] * inv; x.w = o[tq][db][3] * inv;
            *(float4*)(orow + db * 16 + 4 * g) = x;
        }
    }
}

extern "C" void kernel_launch(void* const* d_in, const int* in_sizes, int n_in,
                              void* d_out, int out_size, void* d_ws, size_t ws_size,
                              hipStream_t stream) {
    const float* q = (const float*)d_in[0];
    const float* k = (const float*)d_in[1];
    const float* v = (const float*)d_in[2];
    const float* gam = (const float*)d_in[3];
    float* out = (float*)d_out;

    char* w = (char*)d_ws;
    const size_t bigN = (size_t)NH * NTOK * DD * sizeof(unsigned short);
    unsigned short* Kbuf = (unsigned short*)w;  w += bigN;
    unsigned short* Vtb  = (unsigned short*)w;  w += bigN;
    unsigned short* K1   = (unsigned short*)w;  w += (size_t)NH * 1024 * DD * 2;
    unsigned short* Vt1  = (unsigned short*)w;  w += (size_t)NH * 1024 * DD * 2;
    unsigned short* K2   = (unsigned short*)w;  w += (size_t)NH * 128 * DD * 2;
    unsigned short* Vt2  = (unsigned short*)w;  w += (size_t)NH * 128 * DD * 2;
    unsigned short* K3   = (unsigned short*)w;  w += (size_t)NH * 32 * DD * 2;
    unsigned short* Vt3  = (unsigned short*)w;  w += (size_t)NH * 32 * DD * 2;

    prep_kv1<<<NH * (NTOK / 64), 256, 0, stream>>>(k, v, Kbuf, Vtb, K1, Vt1);
    pool2_b<<<NH * 128 * DD / 256, 256, 0, stream>>>(K1, Vt1, K2, Vt2);
    pool3_b<<<NH * 32 * DD / 256, 256, 0, stream>>>(K2, Vt2, K3, Vt3);

    attn_mfma<<<NH * 128, 64, 0, stream>>>(q, Kbuf, Vtb, K1, Vt1, K2, Vt2, K3, Vt3, gam, out);
}